// Round 1
// baseline (907.715 us; speedup 1.0000x reference)
//
#include <hip/hip_runtime.h>
#include <math.h>

#define GD 128  // dynamic/feature dim

// Y[r][c] = sum_k X[r][k] * W[k][c]   (X: nrows x 128, W: 128 x 128 row-major)
// 256 threads/block: 8 rows per block, 32 threads per row, 4 cols per thread.
// In-place safe (Y == X allowed): each block stages its rows in LDS first.
__global__ __launch_bounds__(256) void gemm_xw(const float* __restrict__ X,
                                               const float* __restrict__ W,
                                               float* __restrict__ Y, int nrows) {
    __shared__ float xs[8 * GD];
    int t = threadIdx.x;
    int r0 = blockIdx.x * 8;
    {
        int srow = r0 + (t >> 5);
        float4 v = make_float4(0.f, 0.f, 0.f, 0.f);
        if (srow < nrows) v = ((const float4*)(X + (size_t)srow * GD))[t & 31];
        ((float4*)xs)[t] = v;
    }
    __syncthreads();
    int c4 = (t & 31) * 4;
    const float* xrow = xs + (t >> 5) * GD;
    float a0 = 0.f, a1 = 0.f, a2 = 0.f, a3 = 0.f;
#pragma unroll 8
    for (int k = 0; k < GD; ++k) {
        float xv = xrow[k];
        float4 w = *(const float4*)(W + k * GD + c4);
        a0 += xv * w.x; a1 += xv * w.y; a2 += xv * w.z; a3 += xv * w.w;
    }
    int orow = r0 + (t >> 5);
    if (orow < nrows) {
        float4 o = make_float4(a0, a1, a2, a3);
        *(float4*)(Y + (size_t)orow * GD + c4) = o;
    }
}

// agg[erow[e]][c] += S[ecol[e]][c] * ev[e]  — one thread per (edge, column)
__global__ __launch_bounds__(256) void scatter_add(const float* __restrict__ S,
                                                   const int* __restrict__ erow,
                                                   const int* __restrict__ ecol,
                                                   const float* __restrict__ ev,
                                                   float* __restrict__ agg, int nedges) {
    long long idx = (long long)blockIdx.x * 256 + threadIdx.x;
    int e = (int)(idx >> 7);
    if (e >= nedges) return;
    int c = (int)(idx & 127);
    int row = erow[e];
    int col = ecol[e];
    float v = ev[e];
    atomicAdd(agg + (size_t)row * GD + c, S[(size_t)col * GD + c] * v);
}

// out = relu(0.1*agg + 0.9*init), float4-vectorized
__global__ __launch_bounds__(256) void blend_relu(const float* __restrict__ agg,
                                                  const float* __restrict__ init,
                                                  float* __restrict__ out, int n4) {
    int i = blockIdx.x * 256 + threadIdx.x;
    if (i >= n4) return;
    float4 a = ((const float4*)agg)[i];
    float4 b = ((const float4*)init)[i];
    float4 o;
    o.x = fmaxf(0.1f * a.x + 0.9f * b.x, 0.0f);
    o.y = fmaxf(0.1f * a.y + 0.9f * b.y, 0.0f);
    o.z = fmaxf(0.1f * a.z + 0.9f * b.z, 0.0f);
    o.w = fmaxf(0.1f * a.w + 0.9f * b.w, 0.0f);
    ((float4*)out)[i] = o;
}

// One block (128 threads) per output row b:
//   ce   = relu(0.1*agg2[codeid[b]] + 0.9*init[codeid[b]])          [128]
//   in1  = [patient[pid] (128) | timediffs[b] (1) | features[b] (128)]  [257]
//   h[j] = tanh(b_ih[j] + b_hh[j] + sum_k in1[k]*W_ih[j][k] + sum_k ce[k]*W_hh[j][k])
//   out[b] = h / max(||h||_2, 1e-12)
__global__ __launch_bounds__(128) void final_rnn(const float* __restrict__ agg2,
                                                 const float* __restrict__ init,
                                                 const float* __restrict__ patient,
                                                 const float* __restrict__ timediffs,
                                                 const float* __restrict__ features,
                                                 const float* __restrict__ W_ih,
                                                 const float* __restrict__ b_ih,
                                                 const float* __restrict__ W_hh,
                                                 const float* __restrict__ b_hh,
                                                 const int* __restrict__ codeid,
                                                 const int* __restrict__ patientid,
                                                 float* __restrict__ out) {
    __shared__ float in1[257];
    __shared__ float ce[GD];
    __shared__ float red[GD];
    int b = blockIdx.x;
    int j = threadIdx.x;  // 0..127
    int cid = codeid[b];
    int pid = patientid[0];

    ce[j] = fmaxf(0.1f * agg2[(size_t)cid * GD + j] + 0.9f * init[(size_t)cid * GD + j], 0.0f);
    in1[j] = patient[(size_t)pid * GD + j];
    in1[GD + 1 + j] = features[(size_t)b * GD + j];
    if (j == 0) in1[GD] = timediffs[b];
    __syncthreads();

    float acc = b_ih[j] + b_hh[j];
    const float* wih = W_ih + (size_t)j * 257;
#pragma unroll 8
    for (int k = 0; k < 257; ++k) acc += in1[k] * wih[k];
    const float* whh = W_hh + (size_t)j * GD;
#pragma unroll 8
    for (int k = 0; k < GD; ++k) acc += ce[k] * whh[k];
    float h = tanhf(acc);

    red[j] = h * h;
    __syncthreads();
    for (int s = 64; s > 0; s >>= 1) {
        if (j < s) red[j] += red[j + s];
        __syncthreads();
    }
    float nrm = fmaxf(sqrtf(red[0]), 1e-12f);
    out[(size_t)b * GD + j] = h / nrm;
}

extern "C" void kernel_launch(void* const* d_in, const int* in_sizes, int n_in,
                              void* d_out, int out_size, void* d_ws, size_t ws_size,
                              hipStream_t stream) {
    const float* code_dynamic = (const float*)d_in[0];
    const float* init_cd      = (const float*)d_in[1];
    const float* patient      = (const float*)d_in[2];
    const float* timediffs    = (const float*)d_in[3];
    const float* features     = (const float*)d_in[4];
    const float* edge_val     = (const float*)d_in[5];
    const float* W1           = (const float*)d_in[6];
    const float* W2           = (const float*)d_in[7];
    const float* W_ih         = (const float*)d_in[8];
    const float* b_ih         = (const float*)d_in[9];
    const float* W_hh         = (const float*)d_in[10];
    const float* b_hh         = (const float*)d_in[11];
    const int* edge_row       = (const int*)d_in[12];
    const int* edge_col       = (const int*)d_in[13];
    const int* codeid         = (const int*)d_in[14];
    const int* patientid      = (const int*)d_in[15];

    int N = in_sizes[0] / GD;   // 60000
    int E = in_sizes[5];        // 600000
    int B = in_sizes[14];       // 256
    size_t nd = (size_t)N * GD;

    float* bufA = (float*)d_ws;       // support / x  (N*128 f32)
    float* bufB = bufA + nd;          // agg          (N*128 f32)

    int gemm_blocks  = (N + 7) / 8;
    int scat_blocks  = (int)(((long long)E * GD + 255) / 256);
    int blend_blocks = (int)((nd / 4 + 255) / 256);

    // ---- layer 1 ----
    gemm_xw<<<gemm_blocks, 256, 0, stream>>>(code_dynamic, W1, bufA, N);
    hipMemsetAsync(bufB, 0, nd * sizeof(float), stream);
    scatter_add<<<scat_blocks, 256, 0, stream>>>(bufA, edge_row, edge_col, edge_val, bufB, E);
    blend_relu<<<blend_blocks, 256, 0, stream>>>(bufB, init_cd, bufA, (int)(nd / 4));

    // ---- layer 2 ----
    gemm_xw<<<gemm_blocks, 256, 0, stream>>>(bufA, W2, bufA, N);   // in-place safe
    hipMemsetAsync(bufB, 0, nd * sizeof(float), stream);
    scatter_add<<<scat_blocks, 256, 0, stream>>>(bufA, edge_row, edge_col, edge_val, bufB, E);

    // ---- RNNCell + L2 normalize (only codeid rows of layer-2 output needed) ----
    final_rnn<<<B, 128, 0, stream>>>(bufB, init_cd, patient, timediffs, features,
                                     W_ih, b_ih, W_hh, b_hh, codeid, patientid,
                                     (float*)d_out);
}

// Round 2
// 375.480 us; speedup vs baseline: 2.4175x; 2.4175x over previous
//
#include <hip/hip_runtime.h>
#include <math.h>

#define GD 128  // dynamic/feature dim

// ---------------- dependency-pruning infrastructure ----------------

__global__ __launch_bounds__(256) void mark_codeids(const int* __restrict__ codeid, int B,
                                                    int* __restrict__ mark) {
    int i = blockIdx.x * 256 + threadIdx.x;
    if (i < B) mark[codeid[i]] = 1;
}

// For each edge e: if markIn[erow[e]] -> append e to list, set markOut[ecol[e]]
__global__ __launch_bounds__(256) void filter_edges(const int* __restrict__ erow,
                                                    const int* __restrict__ ecol, int E,
                                                    const int* __restrict__ markIn,
                                                    int* __restrict__ markOut,
                                                    int* __restrict__ list,
                                                    int* __restrict__ cnt) {
    int e = blockIdx.x * 256 + threadIdx.x;
    if (e >= E) return;
    if (markIn[erow[e]]) {
        int p = atomicAdd(cnt, 1);
        if (p < E) list[p] = e;
        markOut[ecol[e]] = 1;
    }
}

__global__ __launch_bounds__(256) void compact_rows(const int* __restrict__ mark0,
                                                    const int* __restrict__ mark1, int N,
                                                    int* __restrict__ rows0, int* __restrict__ cnt0,
                                                    int* __restrict__ rows1, int* __restrict__ cnt1) {
    int r = blockIdx.x * 256 + threadIdx.x;
    if (r >= N) return;
    if (mark0[r]) rows0[atomicAdd(cnt0, 1)] = r;
    if (mark1[r]) rows1[atomicAdd(cnt1, 1)] = r;
}

// ---------------- compute kernels (grid-stride, device-count driven) ----------------

// Y[rows[i]] = X[rows[i]] @ W for i < *cntp. 8 rows/block-iteration, 32 thr/row.
// In-place safe (X==Y): rows are staged into LDS before any store.
__global__ __launch_bounds__(256) void gemm_rows(const float* __restrict__ X,
                                                 const float* __restrict__ W,
                                                 float* __restrict__ Y,
                                                 const int* __restrict__ rows,
                                                 const int* __restrict__ cntp) {
    __shared__ float xs[8 * GD];
    __shared__ int rid[8];
    int t = threadIdx.x;
    int cnt = *cntp;
    int ngroups = (cnt + 7) >> 3;
    for (int g = blockIdx.x; g < ngroups; g += gridDim.x) {
        if (t < 8) {
            int gi = g * 8 + t;
            rid[t] = (gi < cnt) ? rows[gi] : -1;
        }
        __syncthreads();
        int r = rid[t >> 5];
        if (r >= 0) ((float4*)xs)[t] = ((const float4*)(X + (size_t)r * GD))[t & 31];
        __syncthreads();
        int c4 = (t & 31) * 4;
        const float* xrow = xs + (t >> 5) * GD;
        float a0 = 0.f, a1 = 0.f, a2 = 0.f, a3 = 0.f;
#pragma unroll 8
        for (int k = 0; k < GD; ++k) {
            float xv = xrow[k];
            float4 w = *(const float4*)(W + k * GD + c4);
            a0 += xv * w.x; a1 += xv * w.y; a2 += xv * w.z; a3 += xv * w.w;
        }
        if (r >= 0) *(float4*)(Y + (size_t)r * GD + c4) = make_float4(a0, a1, a2, a3);
        // next iteration's first __syncthreads() protects rid/xs reuse
    }
}

__global__ __launch_bounds__(256) void zero_rows(float* __restrict__ buf,
                                                 const int* __restrict__ rows,
                                                 const int* __restrict__ cntp) {
    int cnt = *cntp;
    int total = cnt * 32;  // float4 per thread
    for (int i = blockIdx.x * 256 + threadIdx.x; i < total; i += gridDim.x * 256) {
        int r = rows[i >> 5];
        ((float4*)(buf + (size_t)r * GD))[i & 31] = make_float4(0.f, 0.f, 0.f, 0.f);
    }
}

__global__ __launch_bounds__(256) void zero_rows_n(float* __restrict__ buf,
                                                   const int* __restrict__ rows, int n) {
    int total = n * 32;
    for (int i = blockIdx.x * 256 + threadIdx.x; i < total; i += gridDim.x * 256) {
        int r = rows[i >> 5];
        ((float4*)(buf + (size_t)r * GD))[i & 31] = make_float4(0.f, 0.f, 0.f, 0.f);
    }
}

// agg[erow[e]][c] += S[ecol[e]][c] * ev[e] over filtered edge list
__global__ __launch_bounds__(256) void scatter_list(const float* __restrict__ S,
                                                    const int* __restrict__ list,
                                                    const int* __restrict__ cntp,
                                                    const int* __restrict__ erow,
                                                    const int* __restrict__ ecol,
                                                    const float* __restrict__ ev,
                                                    float* __restrict__ agg) {
    int cnt = *cntp;
    long long total = (long long)cnt * GD;
    for (long long i = (long long)blockIdx.x * 256 + threadIdx.x; i < total;
         i += (long long)gridDim.x * 256) {
        int e = list[(int)(i >> 7)];
        int c = (int)(i & 127);
        atomicAdd(agg + (size_t)erow[e] * GD + c, S[(size_t)ecol[e] * GD + c] * ev[e]);
    }
}

// out[rows[i]] = relu(0.1*agg[rows[i]] + 0.9*init[rows[i]])
__global__ __launch_bounds__(256) void blend_rows(const float* __restrict__ agg,
                                                  const float* __restrict__ init,
                                                  float* __restrict__ out,
                                                  const int* __restrict__ rows,
                                                  const int* __restrict__ cntp) {
    int cnt = *cntp;
    int total = cnt * 32;
    for (int i = blockIdx.x * 256 + threadIdx.x; i < total; i += gridDim.x * 256) {
        int r = rows[i >> 5];
        int c = i & 31;
        float4 a = ((const float4*)(agg + (size_t)r * GD))[c];
        float4 b = ((const float4*)(init + (size_t)r * GD))[c];
        float4 o;
        o.x = fmaxf(0.1f * a.x + 0.9f * b.x, 0.0f);
        o.y = fmaxf(0.1f * a.y + 0.9f * b.y, 0.0f);
        o.z = fmaxf(0.1f * a.z + 0.9f * b.z, 0.0f);
        o.w = fmaxf(0.1f * a.w + 0.9f * b.w, 0.0f);
        ((float4*)(out + (size_t)r * GD))[c] = o;
    }
}

// One block (128 threads) per output row b (same as validated baseline).
__global__ __launch_bounds__(128) void final_rnn(const float* __restrict__ agg2,
                                                 const float* __restrict__ init,
                                                 const float* __restrict__ patient,
                                                 const float* __restrict__ timediffs,
                                                 const float* __restrict__ features,
                                                 const float* __restrict__ W_ih,
                                                 const float* __restrict__ b_ih,
                                                 const float* __restrict__ W_hh,
                                                 const float* __restrict__ b_hh,
                                                 const int* __restrict__ codeid,
                                                 const int* __restrict__ patientid,
                                                 float* __restrict__ out) {
    __shared__ float in1[257];
    __shared__ float ce[GD];
    __shared__ float red[GD];
    int b = blockIdx.x;
    int j = threadIdx.x;
    int cid = codeid[b];
    int pid = patientid[0];

    ce[j] = fmaxf(0.1f * agg2[(size_t)cid * GD + j] + 0.9f * init[(size_t)cid * GD + j], 0.0f);
    in1[j] = patient[(size_t)pid * GD + j];
    in1[GD + 1 + j] = features[(size_t)b * GD + j];
    if (j == 0) in1[GD] = timediffs[b];
    __syncthreads();

    float acc = b_ih[j] + b_hh[j];
    const float* wih = W_ih + (size_t)j * 257;
#pragma unroll 8
    for (int k = 0; k < 257; ++k) acc += in1[k] * wih[k];
    const float* whh = W_hh + (size_t)j * GD;
#pragma unroll 8
    for (int k = 0; k < GD; ++k) acc += ce[k] * whh[k];
    float h = tanhf(acc);

    red[j] = h * h;
    __syncthreads();
    for (int s = 64; s > 0; s >>= 1) {
        if (j < s) red[j] += red[j + s];
        __syncthreads();
    }
    float nrm = fmaxf(sqrtf(red[0]), 1e-12f);
    out[(size_t)b * GD + j] = h / nrm;
}

extern "C" void kernel_launch(void* const* d_in, const int* in_sizes, int n_in,
                              void* d_out, int out_size, void* d_ws, size_t ws_size,
                              hipStream_t stream) {
    const float* code_dynamic = (const float*)d_in[0];
    const float* init_cd      = (const float*)d_in[1];
    const float* patient      = (const float*)d_in[2];
    const float* timediffs    = (const float*)d_in[3];
    const float* features     = (const float*)d_in[4];
    const float* edge_val     = (const float*)d_in[5];
    const float* W1           = (const float*)d_in[6];
    const float* W2           = (const float*)d_in[7];
    const float* W_ih         = (const float*)d_in[8];
    const float* b_ih         = (const float*)d_in[9];
    const float* W_hh         = (const float*)d_in[10];
    const float* b_hh         = (const float*)d_in[11];
    const int* edge_row       = (const int*)d_in[12];
    const int* edge_col       = (const int*)d_in[13];
    const int* codeid         = (const int*)d_in[14];
    const int* patientid      = (const int*)d_in[15];

    int N = in_sizes[0] / GD;   // 60000
    int E = in_sizes[5];        // 600000
    int B = in_sizes[14];       // 256
    size_t nd = (size_t)N * GD;

    // workspace layout
    float* bufA = (float*)d_ws;          // support / x1   (N*128 f32)
    float* bufB = bufA + nd;             // agg            (N*128 f32)
    int* list1  = (int*)(bufB + nd);     // E
    int* list2  = list1 + E;             // E
    int* mark0  = list2 + E;             // N  -- zeroed region starts here
    int* mark1  = mark0 + N;             // N
    int* mark2  = mark1 + N;             // N
    int* rows0  = mark2 + N;             // N
    int* rows1  = rows0 + N;             // N
    int* cnts   = rows1 + N;             // 8 ints: [cntE2, cntE1, cntR0, cntR1]

    // zero marks + counters in one memset (rows0/rows1 don't need it but are contiguous)
    hipMemsetAsync(mark0, 0, ((size_t)5 * N + 8) * sizeof(int), stream);

    int eb = (E + 255) / 256;
    int nb = (N + 255) / 256;

    // dependency cone: codeid rows -> edges2 -> needed1 rows -> edges1 -> needed0 rows
    mark_codeids<<<(B + 255) / 256, 256, 0, stream>>>(codeid, B, mark2);
    filter_edges<<<eb, 256, 0, stream>>>(edge_row, edge_col, E, mark2, mark1, list2, &cnts[0]);
    filter_edges<<<eb, 256, 0, stream>>>(edge_row, edge_col, E, mark1, mark0, list1, &cnts[1]);
    compact_rows<<<nb, 256, 0, stream>>>(mark0, mark1, N, rows0, &cnts[2], rows1, &cnts[3]);

    // layer 1 (only needed0 rows / edges1 / needed1 rows)
    gemm_rows<<<1024, 256, 0, stream>>>(code_dynamic, W1, bufA, rows0, &cnts[2]);
    zero_rows<<<256, 256, 0, stream>>>(bufB, rows1, &cnts[3]);
    scatter_list<<<2048, 256, 0, stream>>>(bufA, list1, &cnts[1], edge_row, edge_col, edge_val, bufB);
    blend_rows<<<256, 256, 0, stream>>>(bufB, init_cd, bufA, rows1, &cnts[3]);

    // layer 2 (only needed1 rows / edges2 / codeid rows)
    gemm_rows<<<1024, 256, 0, stream>>>(bufA, W2, bufA, rows1, &cnts[3]);  // in-place safe
    zero_rows_n<<<32, 256, 0, stream>>>(bufB, codeid, B);
    scatter_list<<<2048, 256, 0, stream>>>(bufA, list2, &cnts[0], edge_row, edge_col, edge_val, bufB);

    // RNNCell + L2 normalize
    final_rnn<<<B, 128, 0, stream>>>(bufB, init_cd, patient, timediffs, features,
                                     W_ih, b_ih, W_hh, b_hh, codeid, patientid,
                                     (float*)d_out);
}